// Round 1
// baseline (43.504 us; speedup 1.0000x reference)
//
#include <hip/hip_runtime.h>

// Problem constants (from reference)
#define VX 64
#define VY 64
#define VZ 64
#define VCNT (VX * VY * VZ)   // 262144
#define NB 2
#define NT 128
#define HWPIX 65536           // C*H*W = 1*256*256
#define EPS 1e-6f

// ---------------------------------------------------------------------------
// Kernel 1: per-slice mean. One block per (b,t) slice (256 blocks).
// 256 threads, each reads 64 float4 (256 floats), tree-reduce.
// ---------------------------------------------------------------------------
__global__ __launch_bounds__(256) void slice_mean_kernel(
    const float* __restrict__ slices, float* __restrict__ means)
{
    const int s = blockIdx.x;  // 0..255  (b*NT + t)
    const float4* p = (const float4*)(slices + (size_t)s * HWPIX);

    float acc = 0.0f;
#pragma unroll
    for (int i = 0; i < 64; ++i) {
        float4 v = p[i * 256 + threadIdx.x];
        acc += (v.x + v.y) + (v.z + v.w);
    }
    // wave (64-lane) butterfly reduce
#pragma unroll
    for (int off = 32; off > 0; off >>= 1)
        acc += __shfl_down(acc, off, 64);

    __shared__ float ws[4];
    const int lane = threadIdx.x & 63;
    const int wid  = threadIdx.x >> 6;
    if (lane == 0) ws[wid] = acc;
    __syncthreads();
    if (threadIdx.x == 0) {
        float tot = (ws[0] + ws[1]) + (ws[2] + ws[3]);
        means[s] = tot * (1.0f / (float)HWPIX);
    }
}

// ---------------------------------------------------------------------------
// Kernel 2: voxel reconstruction.
// Grid: NB * VCNT / 256 = 2048 blocks, 256 threads, 1 voxel/thread.
// Prologue gathers the 128 (coord.xyz, mean) tuples for this batch into LDS.
// ---------------------------------------------------------------------------
__global__ __launch_bounds__(256) void recon_kernel(
    const float* __restrict__ transforms,
    const int*   __restrict__ sidx,
    const float* __restrict__ means,
    float*       __restrict__ out)
{
    __shared__ float4 ct[NT];  // x, y, z, mean

    const int blocksPerB = VCNT / 256;          // 1024
    const int b     = blockIdx.x / blocksPerB;  // 0..1
    const int vbase = (blockIdx.x % blocksPerB) * 256;

    if (threadIdx.x < NT) {
        const int t   = threadIdx.x;
        const int idx = sidx[b * NT + t];
        const float* tr = transforms + (size_t)(b * NT + idx) * 6;
        float4 c;
        c.x = tr[0];
        c.y = tr[1];
        c.z = tr[2];
        c.w = means[b * NT + idx];
        ct[t] = c;
    }
    __syncthreads();

    const int v  = vbase + threadIdx.x;
    const float fx = (float)(v >> 12);        // i  (vy*vz = 4096)
    const float fy = (float)((v >> 6) & 63);  // j
    const float fz = (float)(v & 63);         // k

    float wsum = 0.0f, acc = 0.0f;
#pragma unroll 8
    for (int t = 0; t < NT; ++t) {
        float4 c = ct[t];  // uniform address -> LDS broadcast, no conflicts
        float dx = fx - c.x;
        float dy = fy - c.y;
        float dz = fz - c.z;
        float d2 = fmaf(dx, dx, fmaf(dy, dy, dz * dz));
        float dist = __builtin_amdgcn_sqrtf(d2);       // dist >= ~0.866
        float w = __expf(__builtin_amdgcn_rcpf(dist + EPS));
        wsum += w;
        acc  = fmaf(w, c.w, acc);
    }

    out[(size_t)b * VCNT + v] = acc / wsum;
}

// ---------------------------------------------------------------------------
extern "C" void kernel_launch(void* const* d_in, const int* in_sizes, int n_in,
                              void* d_out, int out_size, void* d_ws, size_t ws_size,
                              hipStream_t stream)
{
    const float* slices     = (const float*)d_in[0];  // (2,128,1,256,256) f32
    const float* transforms = (const float*)d_in[1];  // (2,128,6) f32
    const int*   sidx       = (const int*)d_in[2];    // (2,128) i32
    float* out   = (float*)d_out;                     // (2,1,64,64,64) f32
    float* means = (float*)d_ws;                      // 256 floats scratch

    slice_mean_kernel<<<NB * NT, 256, 0, stream>>>(slices, means);
    recon_kernel<<<NB * VCNT / 256, 256, 0, stream>>>(transforms, sidx, means, out);
}

// Round 2
// 33.862 us; speedup vs baseline: 1.2847x; 1.2847x over previous
//
#include <hip/hip_runtime.h>

#define VCNT 262144           // 64^3
#define NB 2
#define NT 128
#define HWPIX 65536           // 1*256*256
#define LN2 0.69314718055994531f

typedef float f32x2 __attribute__((ext_vector_type(2)));

static __device__ __forceinline__ float fast_exp2(float x) {
#if __has_builtin(__builtin_amdgcn_exp2f)
    return __builtin_amdgcn_exp2f(x);
#else
    float r; asm("v_exp_f32 %0, %1" : "=v"(r) : "v"(x)); return r;
#endif
}
static __device__ __forceinline__ float fast_rsq(float x) {
#if __has_builtin(__builtin_amdgcn_rsqf)
    return __builtin_amdgcn_rsqf(x);
#else
    float r; asm("v_rsq_f32 %0, %1" : "=v"(r) : "v"(x)); return r;
#endif
}

// ---------------------------------------------------------------------------
// Kernel 1: partial slice sums. 8 blocks per slice -> 2048 blocks (8/CU).
// Each block sums a contiguous 32 KB chunk (8192 floats).
// partials[s*8 + j] = sum of chunk j of slice s  (== partials[blockIdx.x]).
// ---------------------------------------------------------------------------
__global__ __launch_bounds__(256) void slice_partial_kernel(
    const float* __restrict__ slices, float* __restrict__ partials)
{
    const int s = blockIdx.x >> 3;
    const int j = blockIdx.x & 7;
    const float4* p = (const float4*)(slices + (size_t)s * HWPIX) + j * 2048;

    float acc = 0.0f;
#pragma unroll
    for (int i = 0; i < 8; ++i) {
        float4 v = p[i * 256 + threadIdx.x];
        acc += (v.x + v.y) + (v.z + v.w);
    }
#pragma unroll
    for (int off = 32; off > 0; off >>= 1)
        acc += __shfl_down(acc, off, 64);

    __shared__ float ws[4];
    const int lane = threadIdx.x & 63;
    const int wid  = threadIdx.x >> 6;
    if (lane == 0) ws[wid] = acc;
    __syncthreads();
    if (threadIdx.x == 0)
        partials[blockIdx.x] = (ws[0] + ws[1]) + (ws[2] + ws[3]);
}

// ---------------------------------------------------------------------------
// Kernel 2: voxel reconstruction, 2 voxels/thread packed as f32x2.
// Coordinates pre-scaled by ln2 so  exp(1/dist) == exp2(rsqrt(d2_scaled)).
// Grid: NB*VCNT/512 = 1024 blocks (4/CU, 16 waves/CU).
// ---------------------------------------------------------------------------
__global__ __launch_bounds__(256) void recon_kernel(
    const float* __restrict__ transforms,
    const int*   __restrict__ sidx,
    const float* __restrict__ partials,
    float*       __restrict__ out)
{
    __shared__ float4 ct[NT];  // ln2*x, ln2*y, ln2*z, mean

    const int b  = blockIdx.x >> 9;                           // 512 blocks/batch
    const int v0 = ((blockIdx.x & 511) << 9) + (threadIdx.x << 1);

    if (threadIdx.x < NT) {
        const int idx = sidx[b * NT + threadIdx.x];
        const float* tr = transforms + (size_t)(b * NT + idx) * 6;
        const float* pp = partials   + (size_t)(b * NT + idx) * 8;
        float m = 0.0f;
#pragma unroll
        for (int i = 0; i < 8; ++i) m += pp[i];
        ct[threadIdx.x] = make_float4(tr[0] * LN2, tr[1] * LN2, tr[2] * LN2,
                                      m * (1.0f / (float)HWPIX));
    }
    __syncthreads();

    const float fx = (float)(v0 >> 12) * LN2;
    const float fy = (float)((v0 >> 6) & 63) * LN2;
    const float fzl = (float)(v0 & 63) * LN2;     // v0 even -> pair in same row

    const f32x2 fx2 = {fx, fx};
    const f32x2 fy2 = {fy, fy};
    const f32x2 fz2 = {fzl, fzl + LN2};

    f32x2 wsum = {0.0f, 0.0f};
    f32x2 acc  = {0.0f, 0.0f};

#pragma unroll 4
    for (int t = 0; t < NT; ++t) {
        float4 c = ct[t];                      // uniform addr -> LDS broadcast
        f32x2 dx = fx2 - (f32x2){c.x, c.x};
        f32x2 dy = fy2 - (f32x2){c.y, c.y};
        f32x2 dz = fz2 - (f32x2){c.z, c.z};
        f32x2 d2 = dx * dx;
        d2 += dy * dy;                         // contracts to v_pk_fma_f32
        d2 += dz * dz;
        float w0 = fast_exp2(fast_rsq(d2.x));  // exp(1/dist)
        float w1 = fast_exp2(fast_rsq(d2.y));
        f32x2 w2 = {w0, w1};
        wsum += w2;
        acc  += w2 * (f32x2){c.w, c.w};
    }

    float2 o;
    o.x = acc.x / wsum.x;
    o.y = acc.y / wsum.y;
    *(float2*)(out + (size_t)b * VCNT + v0) = o;
}

// ---------------------------------------------------------------------------
extern "C" void kernel_launch(void* const* d_in, const int* in_sizes, int n_in,
                              void* d_out, int out_size, void* d_ws, size_t ws_size,
                              hipStream_t stream)
{
    const float* slices     = (const float*)d_in[0];  // (2,128,1,256,256) f32
    const float* transforms = (const float*)d_in[1];  // (2,128,6) f32
    const int*   sidx       = (const int*)d_in[2];    // (2,128) i32
    float* out      = (float*)d_out;                  // (2,1,64,64,64) f32
    float* partials = (float*)d_ws;                   // 2048 floats scratch

    slice_partial_kernel<<<NB * NT * 8, 256, 0, stream>>>(slices, partials);
    recon_kernel<<<NB * VCNT / 512, 256, 0, stream>>>(transforms, sidx, partials, out);
}